// Round 1
// baseline (126.924 us; speedup 1.0000x reference)
//
#include <hip/hip_runtime.h>
#include <hip/hip_bf16.h>

// Problem constants (from reference): B=64, T=8000, S=10.
#define B_ 64
#define T_ 8000
#define S_ 10
#define NCHUNK 4              // T split into 4 chunks of 2000 t's (1000 t-pairs)
#define PAIRS_PER_CHUNK 1000  // each thread-pair covers 2 consecutive t's (80B aligned)

// ws layout:
//   partial : [B][NCHUNK][112] floats  (110 used: M[100] then D[10])
//   ws2     : [B] floats (per-batch optimal assignment cost, un-normalized)

// ---------------------------------------------------------------------------
// Kernel 1: accumulate M[i][j] = sum_t (logp - log1mp)[t,i] * tgt[t,j]
//           and      D[i]     = sum_t log1mp[t,i]
// grid (NCHUNK, B) x 256 threads. Each thread owns all 110 accumulators and a
// strided slice of t-pairs (2 t's = 80 B = five 16B-aligned float4 loads per
// input -> fully vectorized, dense/coalesced).
// ---------------------------------------------------------------------------
__global__ __launch_bounds__(256, 1) void pit_cost_kernel(
    const float* __restrict__ pred, const float* __restrict__ tgt,
    float* __restrict__ partial)
{
    const int b     = blockIdx.y;
    const int chunk = blockIdx.x;
    const int tid   = threadIdx.x;

    float acc[110];
#pragma unroll
    for (int v = 0; v < 110; ++v) acc[v] = 0.0f;

    const size_t baseBT = (size_t)b * (T_ * S_);
    const int p0 = chunk * PAIRS_PER_CHUNK;

#pragma unroll
    for (int it = 0; it < 4; ++it) {
        const int rel = it * 256 + tid;
        if (rel < PAIRS_PER_CHUNK) {
            const int p = p0 + rel;
            const size_t off = baseBT + (size_t)p * (2 * S_);
            const float4* P = reinterpret_cast<const float4*>(pred + off);
            const float4* G = reinterpret_cast<const float4*>(tgt + off);
            alignas(16) float pr[20];
            alignas(16) float tg[20];
#pragma unroll
            for (int k = 0; k < 5; ++k) {
                reinterpret_cast<float4*>(pr)[k] = P[k];
                reinterpret_cast<float4*>(tg)[k] = G[k];
            }
#pragma unroll
            for (int u = 0; u < 2; ++u) {
                float d[10];
#pragma unroll
                for (int i = 0; i < 10; ++i) {
                    const float pv = pr[u * 10 + i];
                    const float lm = __logf(1.0f - pv);   // log(1-p)
                    d[i] = __logf(pv) - lm;               // logit(p)
                    acc[100 + i] += lm;                   // D[i]
                }
#pragma unroll
                for (int i = 0; i < 10; ++i) {
#pragma unroll
                    for (int j = 0; j < 10; ++j) {
                        acc[i * 10 + j] += d[i] * tg[u * 10 + j];  // M[i][j]
                    }
                }
            }
        }
    }

    // Reduce 110 accumulators across the block: per-wave butterfly, then
    // cross-wave sum through LDS. lane 0 of each wave holds the wave sum.
    __shared__ float red[4][112];
    const int wave = tid >> 6;
    const int lane = tid & 63;
#pragma unroll
    for (int v = 0; v < 110; ++v) {
        float x = acc[v];
#pragma unroll
        for (int off = 32; off > 0; off >>= 1) x += __shfl_xor(x, off, 64);
        if (lane == 0) red[wave][v] = x;
    }
    __syncthreads();
    if (tid < 110) {
        const float s = red[0][tid] + red[1][tid] + red[2][tid] + red[3][tid];
        partial[((size_t)b * NCHUNK + chunk) * 112 + tid] = s;
    }
}

// ---------------------------------------------------------------------------
// Kernel 2: per batch b -- finalize cost[i][j] = -(M[i][j] + D[i]) (raw, >0),
// then exact min-cost assignment via subset DP over column masks:
//   dp[mask] = min_{j in mask} dp[mask \ j] + cost[popc(mask)-1][j]
// grid B x 256 threads; ws2[b] = dp[full].
// ---------------------------------------------------------------------------
__global__ __launch_bounds__(256, 1) void pit_dp_kernel(
    const float* __restrict__ partial, float* __restrict__ ws2)
{
    const int b   = blockIdx.x;
    const int tid = threadIdx.x;

    __shared__ float Ms[100];
    __shared__ float Ds[10];
    __shared__ float cost[100];
    __shared__ float dp[1024];

    if (tid < 110) {
        const float* pb = partial + (size_t)b * NCHUNK * 112;
        float s = pb[tid] + pb[112 + tid] + pb[224 + tid] + pb[336 + tid];
        if (tid < 100) Ms[tid] = s;
        else           Ds[tid - 100] = s;
    }
    __syncthreads();
    if (tid < 100) cost[tid] = -(Ms[tid] + Ds[tid / 10]);
    if (tid == 0) dp[0] = 0.0f;
    __syncthreads();

    for (int k = 1; k <= 10; ++k) {
        for (int m = tid; m < 1024; m += 256) {
            if (__popc(m) == k) {
                float best = 3.0e38f;
#pragma unroll
                for (int j = 0; j < 10; ++j) {
                    if (m & (1 << j)) {
                        const float c = dp[m ^ (1 << j)] + cost[(k - 1) * 10 + j];
                        best = fminf(best, c);
                    }
                }
                dp[m] = best;
            }
        }
        __syncthreads();
    }
    if (tid == 0) ws2[b] = dp[1023];
}

// ---------------------------------------------------------------------------
// Kernel 3: final mean. out = sum_b ws2[b] / (T * B * S)
// (ws2 holds raw costs = T * pairwise; mean over B*S matched entries.)
// ---------------------------------------------------------------------------
__global__ void pit_final_kernel(const float* __restrict__ ws2,
                                 float* __restrict__ out)
{
    const int lane = threadIdx.x;  // 64 threads, one wave
    float x = ws2[lane];
#pragma unroll
    for (int off = 32; off > 0; off >>= 1) x += __shfl_xor(x, off, 64);
    if (lane == 0) out[0] = x * (1.0f / ((float)T_ * (float)B_ * (float)S_));
}

extern "C" void kernel_launch(void* const* d_in, const int* in_sizes, int n_in,
                              void* d_out, int out_size, void* d_ws, size_t ws_size,
                              hipStream_t stream)
{
    const float* pred = (const float*)d_in[0];
    const float* tgt  = (const float*)d_in[1];
    float* partial = (float*)d_ws;                       // [64][4][112]
    float* ws2     = partial + (size_t)B_ * NCHUNK * 112; // [64]
    float* out     = (float*)d_out;

    pit_cost_kernel<<<dim3(NCHUNK, B_), 256, 0, stream>>>(pred, tgt, partial);
    pit_dp_kernel<<<B_, 256, 0, stream>>>(partial, ws2);
    pit_final_kernel<<<1, 64, 0, stream>>>(ws2, out);
}

// Round 2
// 123.016 us; speedup vs baseline: 1.0318x; 1.0318x over previous
//
#include <hip/hip_runtime.h>
#include <hip/hip_bf16.h>

// Problem constants (from reference): B=64, T=8000, S=10.
#define B_ 64
#define T_ 8000
#define S_ 10
#define NCHUNK 8             // T split into 8 chunks of 1000 t's
#define TPC 1000             // t's per chunk
#define QUADS 250            // threads 0..249 each own 4 consecutive t's (160 B)

// ws layout:
//   partial : [B][NCHUNK][112] floats  (110 used: M[100] then D[10])

// ---------------------------------------------------------------------------
// Kernel 1: accumulate M[i][j] = sum_t (logp - log1mp)[t,i] * tgt[t,j]
//           and      D[i]     = sum_t log1mp[t,i]
// grid (NCHUNK, B) x 256 threads = 512 blocks = 2 blocks/CU (matches the
// 2-waves/SIMD occupancy that ~190 VGPRs allows). Thread tid<250 owns 4
// consecutive t's -> 10 contiguous float4 loads per input, issued before any
// compute so the compiler can keep all 20 loads in flight (memory-bound goal:
// 41 MB read-once at ~6.3 TB/s ~= 6.5 us).
// Also zeroes out[0] (poisoned 0xAA) so kernel 2 can atomicAdd into it.
// ---------------------------------------------------------------------------
__global__ __launch_bounds__(256, 1) void pit_cost_kernel(
    const float* __restrict__ pred, const float* __restrict__ tgt,
    float* __restrict__ partial, float* __restrict__ out)
{
    const int b     = blockIdx.y;
    const int chunk = blockIdx.x;
    const int tid   = threadIdx.x;

    if (b == 0 && chunk == 0 && tid == 0) out[0] = 0.0f;

    float acc[110];
#pragma unroll
    for (int v = 0; v < 110; ++v) acc[v] = 0.0f;

    if (tid < QUADS) {
        const size_t off = (size_t)b * (T_ * S_) + (size_t)chunk * (TPC * S_)
                         + (size_t)tid * 40;
        const float4* P = reinterpret_cast<const float4*>(pred + off);
        const float4* G = reinterpret_cast<const float4*>(tgt + off);
        alignas(16) float pr[40];
        alignas(16) float tg[40];
#pragma unroll
        for (int k = 0; k < 10; ++k) reinterpret_cast<float4*>(pr)[k] = P[k];
#pragma unroll
        for (int k = 0; k < 10; ++k) reinterpret_cast<float4*>(tg)[k] = G[k];

#pragma unroll
        for (int u = 0; u < 4; ++u) {
            float d[10];
#pragma unroll
            for (int i = 0; i < 10; ++i) {
                const float pv = pr[u * 10 + i];
                const float lm = __logf(1.0f - pv);   // log(1-p)
                d[i] = __logf(pv) - lm;               // logit(p)
                acc[100 + i] += lm;                   // D[i]
            }
#pragma unroll
            for (int i = 0; i < 10; ++i) {
#pragma unroll
                for (int j = 0; j < 10; ++j) {
                    acc[i * 10 + j] += d[i] * tg[u * 10 + j];  // M[i][j]
                }
            }
        }
    }

    // Block reduction: per-wave butterfly, then cross-wave sum through LDS.
    __shared__ float red[4][112];
    const int wave = tid >> 6;
    const int lane = tid & 63;
#pragma unroll
    for (int v = 0; v < 110; ++v) {
        float x = acc[v];
#pragma unroll
        for (int off = 32; off > 0; off >>= 1) x += __shfl_xor(x, off, 64);
        if (lane == 0) red[wave][v] = x;
    }
    __syncthreads();
    if (tid < 110) {
        const float s = red[0][tid] + red[1][tid] + red[2][tid] + red[3][tid];
        partial[((size_t)b * NCHUNK + chunk) * 112 + tid] = s;
    }
}

// ---------------------------------------------------------------------------
// Kernel 2: per batch b -- finalize cost[i][j] = -(M[i][j] + D[i]) (raw, >0),
// exact min-cost assignment via subset DP over column masks:
//   dp[mask] = min_{j in mask} dp[mask \ j] + cost[popc(mask)-1][j]
// then atomicAdd the normalized optimum into out[0] (zeroed by kernel 1).
// ---------------------------------------------------------------------------
__global__ __launch_bounds__(256, 1) void pit_dp_kernel(
    const float* __restrict__ partial, float* __restrict__ out)
{
    const int b   = blockIdx.x;
    const int tid = threadIdx.x;

    __shared__ float sum[112];
    __shared__ float cost[100];
    __shared__ float dp[1024];

    if (tid < 110) {
        const float* pb = partial + (size_t)b * NCHUNK * 112;
        float s = 0.0f;
#pragma unroll
        for (int c = 0; c < NCHUNK; ++c) s += pb[c * 112 + tid];
        sum[tid] = s;
    }
    __syncthreads();
    if (tid < 100) cost[tid] = -(sum[tid] + sum[100 + tid / 10]);
    if (tid == 0) dp[0] = 0.0f;
    __syncthreads();

    for (int k = 1; k <= 10; ++k) {
        for (int m = tid; m < 1024; m += 256) {
            if (__popc(m) == k) {
                float best = 3.0e38f;
#pragma unroll
                for (int j = 0; j < 10; ++j) {
                    if (m & (1 << j)) {
                        const float c = dp[m ^ (1 << j)] + cost[(k - 1) * 10 + j];
                        best = fminf(best, c);
                    }
                }
                dp[m] = best;
            }
        }
        __syncthreads();
    }
    if (tid == 0) {
        atomicAdd(out, dp[1023] * (1.0f / ((float)T_ * (float)B_ * (float)S_)));
    }
}

extern "C" void kernel_launch(void* const* d_in, const int* in_sizes, int n_in,
                              void* d_out, int out_size, void* d_ws, size_t ws_size,
                              hipStream_t stream)
{
    const float* pred = (const float*)d_in[0];
    const float* tgt  = (const float*)d_in[1];
    float* partial = (float*)d_ws;          // [64][8][112] floats (~229 KB)
    float* out     = (float*)d_out;

    pit_cost_kernel<<<dim3(NCHUNK, B_), 256, 0, stream>>>(pred, tgt, partial, out);
    pit_dp_kernel<<<B_, 256, 0, stream>>>(partial, out);
}